// Round 10
// baseline (191.181 us; speedup 1.0000x reference)
//
#include <hip/hip_runtime.h>
#include <hip/hip_bf16.h>
#include <math.h>

typedef __attribute__((ext_vector_type(8))) short bf16x8;   // 8 bf16 in 4 VGPRs
typedef __attribute__((ext_vector_type(4))) float f32x4;    // MFMA C/D frag
typedef unsigned short u16;
typedef unsigned int   u32;

#define DEVINL __device__ __forceinline__

// round-to-nearest-even f32 -> bf16 bits
DEVINL u16 f2bf(float x) {
    u32 u = __float_as_uint(x);
    u += 0x7fffu + ((u >> 16) & 1u);
    return (u16)(u >> 16);
}

// async global->LDS, 16B per lane. LDS dest is wave-uniform base + lane*16;
// global address is per-lane arbitrary -> swizzle on the global side.
DEVINL void gl_lds16(const void* g, void* s) {
    __builtin_amdgcn_global_load_lds(
        (const __attribute__((address_space(1))) u32*)g,
        (__attribute__((address_space(3))) u32*)s,
        16, 0, 0);
}

DEVINL f32x4 mfma16(bf16x8 a, bf16x8 b, f32x4 c) {
    return __builtin_amdgcn_mfma_f32_16x16x32_bf16(a, b, c, 0, 0, 0);
}

// ---------------- fused fp32 -> bf16 conversion (x, w_qkv[0:1536], w_out) ----------------
__global__ void cvt3(const float* __restrict__ x, const float* __restrict__ wq,
                     const float* __restrict__ wo,
                     u16* __restrict__ xb, u16* __restrict__ wqb, u16* __restrict__ wob) {
    int i = blockIdx.x * 256 + threadIdx.x;   // float4 index
    const float* s; u16* d; int j;
    if (i < 1048576)      { s = x;  d = xb;  j = i; }
    else if (i < 1441792) { s = wq; d = wqb; j = i - 1048576; }
    else                  { s = wo; d = wob; j = i - 1441792; }
    float4 v = ((const float4*)s)[j];
    ushort4 o;
    o.x = f2bf(v.x); o.y = f2bf(v.y); o.z = f2bf(v.z); o.w = f2bf(v.w);
    ((ushort4*)d)[j] = o;
}

// ------- GEMM C[M,N] = A[M,K] * B[N,K]^T, global_load_lds double-buffered pipeline -------
// ROUND-7 PROVEN (152.7 us total): round-4 structure + T1 XCD swizzle. 64 x BN tile,
// BK=64, 4 waves each 32 x BN/2; 768/512 blocks = 3/2 per CU. Each XCD owns a contiguous
// grid chunk -> per-XCD working set ~4MB = L2-sized. nwg%8==0 (bijective, ERRATA #11 ok).
// Tile k+1 prefetched straight into LDS buf[cur^1] via global_load_lds dwordx4 before
// computing tile k from buf[cur]; single barrier per K-step.
// LDS 16B chunks XOR-swizzled on the GLOBAL side (slot lc holds chunk lc^(row&7)); the
// LDS destination is linear base+lane*16 exactly as global_load_lds requires.
// EP==0: fp32 store to Cf (ld=N). EP==1: qkv scatter epilogue (bf16, Q pre-scaled).
template<int BN, int EP>
__launch_bounds__(256)
__global__ void gemm_rp(const u16* __restrict__ A, const u16* __restrict__ B,
                        const int N, const int K,
                        float* __restrict__ Cf,
                        u16* __restrict__ Qo, u16* __restrict__ Ko, u16* __restrict__ Vo)
{
    constexpr int NB = BN / 32;                    // n-frags per wave / B row-groups per wave
    __shared__ __align__(16) u16 As[2][64 * 64];   // 16 KB
    __shared__ __align__(16) u16 Bs[2][BN * 64];   // 16 or 32 KB
    const int tid  = threadIdx.x;
    const int lane = tid & 63;
    const int quad = lane >> 4;
    const int lcol = lane & 15;
    const int w    = tid >> 6;
    const int wr   = w >> 1, wc = w & 1;
    const int lr   = lane >> 3;        // staging row within 8-row group
    const int lc   = lane & 7;         // staging slot within row
    const int swst = lc ^ lr;          // global chunk loaded into slot lc
    const int rk   = lcol & 7;         // read swizzle key (row&7)

    // T1 XCD swizzle: contiguous chunk of the grid per XCD (nwg % 8 == 0)
    const int nwg = gridDim.x * gridDim.y;
    int bid = blockIdx.y * gridDim.x + blockIdx.x;     // hw dispatch order (x fastest)
    bid = (bid & 7) * (nwg >> 3) + (bid >> 3);
    const int m0 = (bid / gridDim.x) * 64;
    const int n0 = (bid % gridDim.x) * BN;

    f32x4 acc[2][NB];
    for (int mb = 0; mb < 2; mb++)
        for (int nb = 0; nb < NB; nb++)
            for (int i = 0; i < 4; i++) acc[mb][nb][i] = 0.f;

    // per-lane pre-swizzled global source pointers
    const u16* Ap = A + (m0 + w * 16 + lr) * K + swst * 8;
    const u16* Bp = B + (n0 + w * (BN / 4) + lr) * K + swst * 8;

    // prologue: tile 0 -> LDS buf 0 (async, drained by the first barrier)
    for (int j = 0; j < 2; j++)
        gl_lds16(Ap + j * 8 * K, &As[0][(w * 16 + j * 8) * 64]);
    for (int g = 0; g < NB; g++)
        gl_lds16(Bp + g * 8 * K, &Bs[0][(w * (BN / 4) + g * 8) * 64]);
    __syncthreads();

    int cur = 0;
    for (int k0 = 0; k0 < K; k0 += 64) {
        if (k0 + 64 < K) {   // prefetch next tile into the other buffer (max latency cover)
            for (int j = 0; j < 2; j++)
                gl_lds16(Ap + j * 8 * K + k0 + 64, &As[cur ^ 1][(w * 16 + j * 8) * 64]);
            for (int g = 0; g < NB; g++)
                gl_lds16(Bp + g * 8 * K + k0 + 64, &Bs[cur ^ 1][(w * (BN / 4) + g * 8) * 64]);
        }
        // compute tile k0 from buf[cur]
        bf16x8 af[2][2], bfv[NB][2];
        for (int ks = 0; ks < 2; ks++) {
            const int ch = ((ks * 4 + quad) ^ rk) * 8;
            for (int mb = 0; mb < 2; mb++)
                af[mb][ks] = *(const bf16x8*)&As[cur][(wr * 32 + mb * 16 + lcol) * 64 + ch];
            for (int nb = 0; nb < NB; nb++)
                bfv[nb][ks] = *(const bf16x8*)&Bs[cur][(wc * (BN / 2) + nb * 16 + lcol) * 64 + ch];
        }
        for (int ks = 0; ks < 2; ks++)
            for (int mb = 0; mb < 2; mb++)
                for (int nb = 0; nb < NB; nb++)
                    acc[mb][nb] = mfma16(af[mb][ks], bfv[nb][ks], acc[mb][nb]);
        __syncthreads();   // drains prefetch (vmcnt) + fences LDS reads; flip buffers
        cur ^= 1;
    }

    if (EP == 0) {
        for (int mb = 0; mb < 2; mb++)
            for (int nb = 0; nb < NB; nb++) {
                int row = m0 + wr * 32 + mb * 16 + quad * 4;
                int col = n0 + wc * (BN / 2) + nb * 16 + lcol;
                for (int i = 0; i < 4; i++)
                    Cf[(row + i) * N + col] = acc[mb][nb][i];
            }
    } else {
        const float qsc = 0.18033688011112042f;  // (1/sqrt(64)) * log2(e), folded into Q
        for (int mb = 0; mb < 2; mb++)
            for (int nb = 0; nb < NB; nb++)
                for (int i = 0; i < 4; i++) {
                    int row = m0 + wr * 32 + mb * 16 + quad * 4 + i;  // b*2048+s
                    int col = n0 + wc * (BN / 2) + nb * 16 + lcol;    // qkv column
                    int bb = row >> 11, ss = row & 2047;
                    if (col < 1024) {
                        int hh = col >> 6, dd = col & 63;
                        Qo[((bb * 16 + hh) * 2048 + ss) * 64 + dd] = f2bf(acc[mb][nb][i] * qsc);
                    } else if (col < 1280) {
                        int c = col - 1024, hh = c >> 6, dd = c & 63;
                        Ko[((bb * 4 + hh) * 2048 + ss) * 64 + dd] = f2bf(acc[mb][nb][i]);
                    } else {
                        int c = col - 1280, hh = c >> 6, dd = c & 63;
                        Vo[((bb * 4 + hh) * 64 + dd) * 2048 + ss] = f2bf(acc[mb][nb][i]);
                    }
                }
    }
}

// ---------------- flash attention, causal GQA, NO-MAX softmax, KV-SPLIT x2 ----------------
// V-DIRECT, vmcnt-ORDER CORRECTED (resubmission of round 9: infra failure, no signal).
// r4 analysis: attn is LDS-pipe-bound (~34 ds-ops/wave/iter x 16 waves ~= 5000cy ~=
// measured 5300cy/iter); V-direct removes ~30% of LDS ops. r8 failed because K-prefetch
// was issued BEFORE the V loads: vmcnt retires IN ORDER, so PV's wait on bv drained the
// prefetch into every iteration's critical path. Corrected program order: bv0 -> QK
// (covers bv0) -> bv1 -> K-prefetch -> softmax/P (covers bv1) -> PV (vmcnt leaves
// prefetch in flight) -> barrier (drains prefetch, covered by PV). No sched_barrier pins.
// LDS = Ks 32KB + Ps 16KB + Lb = 48.25 KB; bounds (512,4) natural, no spill forcing.
// T5 setprio kept on MFMA clusters.
__launch_bounds__(512, 4)
__global__ void attn_kernel(const u16* __restrict__ Qg, const u16* __restrict__ Kg,
                            const u16* __restrict__ Vtg, u16* __restrict__ Og)
{
    __shared__ __align__(16) u16 Ks[2][2][64 * 64];   // [group][buf] 32 KB
    __shared__ __align__(16) u16 Ps[2][64 * 64];      // [group]      16 KB
    __shared__ float Lb[64];                          // 256 B  => 48.25 KB

    const int tid  = threadIdx.x;
    const int lane = tid & 63;
    const int w8   = tid >> 6;        // 0..7
    const int gpp  = w8 >> 2;         // kv-split group (0/1)
    const int wg   = w8 & 3;          // wave within group
    const int quad = lane >> 4;
    const int lcol = lane & 15;
    const int lr   = lane >> 3;
    const int lc   = lane & 7;
    const int swst = lc ^ lr;
    const int rk   = lcol & 7;
    const int hl   = lcol >> 3;

    const int p  = blockIdx.x;       // pair 0..15
    const int h  = blockIdx.y;
    const int b  = blockIdx.z;
    const int hk = h >> 2;

    const u16* Qp = Qg  + (b * 16 + h) * 2048 * 64;
    const u16* Kp = Kg  + (b * 4 + hk) * 2048 * 64;
    const u16* Vp = Vtg + (b * 4 + hk) * 64 * 2048;

    // P-store base: original index (w*16+quad*4+i)*64 + (((cb*2+hl)^((quad&1)*4+i))<<3)+lc
    // == (p0 + i*64) ^ (((cb*2)^i)<<3)  [all swizzle fields bit-disjoint]
    const int p0 = (wg * 16 + quad * 4) * 64 + ((hl ^ ((quad & 1) << 2)) << 3) + lc;

    float* Ob = (float*)(&Ks[1][0][0]);   // 16 KB combine buffer (valid only post-loop)

    for (int pass = 0; pass < 2; pass++) {
        const int qi = pass ? (31 - p) : p;
        const int q0 = qi * 64;
        const int nt = qi + 1;
        const int nIter = (nt + 1) >> 1;  // common (wave-uniform across block) loop count

        // Q A-fragments straight to registers; once per pass (same rows for both groups)
        bf16x8 aqr[2];
        for (int ks = 0; ks < 2; ks++)
            aqr[ks] = *(const bf16x8*)(Qp + (q0 + wg * 16 + lcol) * 64 + ks * 32 + quad * 8);

        // prologue: this group's K tile 0 (ti = gpp) into buf 0 (XOR-swizzled)
        if (gpp < nt) {
            for (int j = 0; j < 2; j++) {
                const int r = wg * 16 + j * 8 + lr;
                gl_lds16(Kp + (gpp * 64 + r) * 64 + swst * 8, &Ks[gpp][0][wg * 1024 + j * 512]);
            }
        }

        f32x4 o[4];
        float l_p[4];
        for (int db = 0; db < 4; db++)
            for (int i = 0; i < 4; i++) o[db][i] = 0.f;
        for (int i = 0; i < 4; i++) l_p[i] = 0.f;

        __syncthreads();

        for (int it = 0; it < nIter; ++it) {
            const int cur = it & 1;
            const int ti  = 2 * it + gpp;      // this group's tile (may be >= nt: idle)
            const int tin = ti + 2;
            if (ti < nt) {
                const u16* Vt = Vp + ti * 64;

                // kt=0 V B-fragments from global -- FIRST vmem ops of the iteration
                bf16x8 bv0[4];
                for (int db = 0; db < 4; db++)
                    bv0[db] = *(const bf16x8*)(Vt + (db * 16 + lcol) * 2048 + quad * 8);

                // S = Q K^T (covers bv0's L2 latency)
                f32x4 s[4];
                for (int cb = 0; cb < 4; cb++)
                    for (int i = 0; i < 4; i++) s[cb][i] = 0.f;
                __builtin_amdgcn_s_setprio(1);
                for (int ks = 0; ks < 2; ks++) {
                    const int chq = ((ks * 4 + quad) ^ rk) * 8;
                    for (int cb = 0; cb < 4; cb++) {
                        bf16x8 bk = *(const bf16x8*)&Ks[gpp][cur][(cb * 16 + lcol) * 64 + chq];
                        s[cb] = mfma16(aqr[ks], bk, s[cb]);
                    }
                }
                __builtin_amdgcn_s_setprio(0);

                // kt=1 V B-fragments (covered by softmax + P-store)
                bf16x8 bv1[4];
                for (int db = 0; db < 4; db++)
                    bv1[db] = *(const bf16x8*)(Vt + (db * 16 + lcol) * 2048 + 32 + quad * 8);

                // K-prefetch issued AFTER all bv loads: PV's bv waits leave it in flight;
                // it drains only at the barrier, with PV as cover (r8's bug corrected).
                if (tin < nt) {
                    const int nbuf = cur ^ 1;
                    for (int j = 0; j < 2; j++) {
                        const int r = wg * 16 + j * 8 + lr;
                        gl_lds16(Kp + (tin * 64 + r) * 64 + swst * 8,
                                 &Ks[gpp][nbuf][wg * 1024 + j * 512]);
                    }
                }

                // causal mask on the diagonal tile only (owned by group (nt-1)&1)
                if (ti == nt - 1) {
                    for (int cb = 0; cb < 4; cb++)
                        for (int i = 0; i < 4; i++) {
                            const bool masked = (cb * 16 + lcol) > (wg * 16 + quad * 4 + i);
                            s[cb][i] = masked ? -INFINITY : s[cb][i];
                        }
                }

                // no-max softmax: p = exp2(s) via raw v_exp_f32 (exp2(-inf)=0 in HW)
                for (int cb = 0; cb < 4; cb++)
                    for (int i = 0; i < 4; i++) {
                        const float pv = __builtin_amdgcn_exp2f(s[cb][i]);
                        s[cb][i] = pv;
                        l_p[i] += pv;
                    }

                // P -> LDS [r][t] swizzled (1 XOR per store), truncating f32->bf16
                // (wave reads back only its OWN rows -> same-wave lgkmcnt ordering)
                for (int cb = 0; cb < 4; cb++)
                    for (int i = 0; i < 4; i++)
                        Ps[gpp][(p0 + i * 64) ^ (((cb * 2) ^ i) << 3)] =
                            (u16)(__float_as_uint(s[cb][i]) >> 16);

                // O += P V   (ap chunk ((kt*4+quad)^rk)^rk == kt*4+quad matches bv's
                //             global t-chunk kt*32+quad*8 -- r6/r8 correctness-verified)
                __builtin_amdgcn_s_setprio(1);
                {
                    const int chp0 = (quad ^ rk) * 8;
                    bf16x8 ap = *(const bf16x8*)&Ps[gpp][(wg * 16 + lcol) * 64 + chp0];
                    for (int db = 0; db < 4; db++)
                        o[db] = mfma16(ap, bv0[db], o[db]);
                }
                {
                    const int chp1 = ((4 + quad) ^ rk) * 8;
                    bf16x8 ap = *(const bf16x8*)&Ps[gpp][(wg * 16 + lcol) * 64 + chp1];
                    for (int db = 0; db < 4; db++)
                        o[db] = mfma16(ap, bv1[db], o[db]);
                }
                __builtin_amdgcn_s_setprio(0);
            }
            __syncthreads();   // single barrier per common iter: drains prefetch, flips bufs
        }

        // ---- combine the two kv-halves (partial O and l simply add; no max to merge) ----
        float lrow[4];
        for (int i = 0; i < 4; i++) {
            float l = l_p[i];
            for (int x = 1; x < 16; x <<= 1) l += __shfl_xor(l, x);
            lrow[i] = l;
        }
        if (gpp == 1) {
            for (int i = 0; i < 4; i++) {
                const int row = wg * 16 + quad * 4 + i;
                for (int db = 0; db < 4; db++)
                    Ob[row * 64 + db * 16 + lcol] = o[db][i];
                if (lcol == 0) Lb[row] = lrow[i];
            }
        }
        __syncthreads();
        if (gpp == 0) {
            for (int i = 0; i < 4; i++) {
                const int row = wg * 16 + quad * 4 + i;
                const float inv = 1.0f / (lrow[i] + Lb[row]);
                const int srow = q0 + row;
                for (int db = 0; db < 4; db++) {
                    const float val = (o[db][i] + Ob[row * 64 + db * 16 + lcol]) * inv;
                    Og[(b * 2048 + srow) * 1024 + h * 64 + db * 16 + lcol] = f2bf(val);
                }
            }
        }
        __syncthreads();   // protect Ob/Lb region before next pass restages Ks[1]
    }
}

extern "C" void kernel_launch(void* const* d_in, const int* in_sizes, int n_in,
                              void* d_out, int out_size, void* d_ws, size_t ws_size,
                              hipStream_t stream) {
    const float* x     = (const float*)d_in[0];   // [2,2048,1024]
    const float* w_qkv = (const float*)d_in[1];   // [3584,1024]; only rows 0..1535 used
    const float* w_out = (const float*)d_in[2];   // [1024,1024]
    float* out = (float*)d_out;                   // [2,2048,1024] fp32
    char* ws = (char*)d_ws;

    u16* xb  = (u16*)(ws);                        // 8 MB  x as bf16 [4096,1024]
    u16* wqb = (u16*)(ws + 8  * 1024 * 1024);     // 3 MB  w_qkv[0:1536] bf16
    u16* wob = (u16*)(ws + 11 * 1024 * 1024);     // 2 MB  w_out bf16
    u16* qb  = (u16*)(ws + 13 * 1024 * 1024);     // 8 MB  Q [b,h,s,d] (pre-scaled)
    u16* kb  = (u16*)(ws + 21 * 1024 * 1024);     // 2 MB  K [b,hk,s,d]
    u16* vtb = (u16*)(ws + 23 * 1024 * 1024);     // 2 MB  V^T [b,hk,d,s]
    u16* aob = (u16*)(ws);                        // 8 MB  attn out bf16 (reuses xb)

    cvt3<<<6656, 256, 0, stream>>>(x, w_qkv, w_out, xb, wqb, wob);

    // QKV projection: 64x128 tiles -> 12 x 64 = 768 blocks (3/CU), XCD-swizzled
    gemm_rp<128, 1><<<dim3(12, 64), 256, 0, stream>>>(xb, wqb, 1536, 1024,
                                                      nullptr, qb, kb, vtb);
    // attention: 512 threads = 2 kv-split groups x 4 waves; V direct from global
    // (vmcnt-order corrected); 48.25 KB LDS
    attn_kernel<<<dim3(16, 16, 2), 512, 0, stream>>>(qb, kb, vtb, aob);
    // output projection: 64x128 tiles -> 8 x 64 = 512 blocks (2/CU), XCD-swizzled
    gemm_rp<128, 0><<<dim3(8, 64), 256, 0, stream>>>(aob, wob, 1024, 1024,
                                                     out, nullptr, nullptr, nullptr);
}

// Round 11
// 149.233 us; speedup vs baseline: 1.2811x; 1.2811x over previous
//
#include <hip/hip_runtime.h>
#include <hip/hip_bf16.h>
#include <math.h>

typedef __attribute__((ext_vector_type(8))) short bf16x8;   // 8 bf16 in 4 VGPRs
typedef __attribute__((ext_vector_type(4))) float f32x4;    // MFMA C/D frag
typedef unsigned short u16;
typedef unsigned int   u32;

#define DEVINL __device__ __forceinline__

// round-to-nearest-even f32 -> bf16 bits
DEVINL u16 f2bf(float x) {
    u32 u = __float_as_uint(x);
    u += 0x7fffu + ((u >> 16) & 1u);
    return (u16)(u >> 16);
}

// async global->LDS, 16B per lane. LDS dest is wave-uniform base + lane*16;
// global address is per-lane arbitrary -> swizzle on the global side.
DEVINL void gl_lds16(const void* g, void* s) {
    __builtin_amdgcn_global_load_lds(
        (const __attribute__((address_space(1))) u32*)g,
        (__attribute__((address_space(3))) u32*)s,
        16, 0, 0);
}

DEVINL f32x4 mfma16(bf16x8 a, bf16x8 b, f32x4 c) {
    return __builtin_amdgcn_mfma_f32_16x16x32_bf16(a, b, c, 0, 0, 0);
}

// ---------------- fused fp32 -> bf16 conversion (x, w_qkv[0:1536], w_out) ----------------
__global__ void cvt3(const float* __restrict__ x, const float* __restrict__ wq,
                     const float* __restrict__ wo,
                     u16* __restrict__ xb, u16* __restrict__ wqb, u16* __restrict__ wob) {
    int i = blockIdx.x * 256 + threadIdx.x;   // float4 index
    const float* s; u16* d; int j;
    if (i < 1048576)      { s = x;  d = xb;  j = i; }
    else if (i < 1441792) { s = wq; d = wqb; j = i - 1048576; }
    else                  { s = wo; d = wob; j = i - 1441792; }
    float4 v = ((const float4*)s)[j];
    ushort4 o;
    o.x = f2bf(v.x); o.y = f2bf(v.y); o.z = f2bf(v.z); o.w = f2bf(v.w);
    ((ushort4*)d)[j] = o;
}

// ------- GEMM C[M,N] = A[M,K] * B[N,K]^T, global_load_lds double-buffered pipeline -------
// ROUND-7 PROVEN (152.7 us total): round-4 structure + T1 XCD swizzle. 64 x BN tile,
// BK=64, 4 waves each 32 x BN/2. This round: gemm2 runs BN=64 (1024 blocks = 4/CU) --
// the r3->r4 evidence says blocks/CU (barrier-drain overlap) dominates at these shapes,
// and gemm2 at BN=128 was the lowest-occupancy dispatch (2/CU).
// Each XCD owns a contiguous grid chunk -> per-XCD working set <=4MB = L2-sized.
// nwg%8==0 for both grids (bijective, ERRATA #11 ok).
// Tile k+1 prefetched straight into LDS buf[cur^1] via global_load_lds dwordx4 before
// computing tile k from buf[cur]; single barrier per K-step.
// LDS 16B chunks XOR-swizzled on the GLOBAL side (slot lc holds chunk lc^(row&7)); the
// LDS destination is linear base+lane*16 exactly as global_load_lds requires.
// EP==0: fp32 store to Cf (ld=N). EP==1: qkv scatter epilogue (bf16, Q pre-scaled).
template<int BN, int EP>
__launch_bounds__(256)
__global__ void gemm_rp(const u16* __restrict__ A, const u16* __restrict__ B,
                        const int N, const int K,
                        float* __restrict__ Cf,
                        u16* __restrict__ Qo, u16* __restrict__ Ko, u16* __restrict__ Vo)
{
    constexpr int NB = BN / 32;                    // n-frags per wave / B row-groups per wave
    __shared__ __align__(16) u16 As[2][64 * 64];   // 16 KB
    __shared__ __align__(16) u16 Bs[2][BN * 64];   // 16 or 32 KB
    const int tid  = threadIdx.x;
    const int lane = tid & 63;
    const int quad = lane >> 4;
    const int lcol = lane & 15;
    const int w    = tid >> 6;
    const int wr   = w >> 1, wc = w & 1;
    const int lr   = lane >> 3;        // staging row within 8-row group
    const int lc   = lane & 7;         // staging slot within row
    const int swst = lc ^ lr;          // global chunk loaded into slot lc
    const int rk   = lcol & 7;         // read swizzle key (row&7)

    // T1 XCD swizzle: contiguous chunk of the grid per XCD (nwg % 8 == 0)
    const int nwg = gridDim.x * gridDim.y;
    int bid = blockIdx.y * gridDim.x + blockIdx.x;     // hw dispatch order (x fastest)
    bid = (bid & 7) * (nwg >> 3) + (bid >> 3);
    const int m0 = (bid / gridDim.x) * 64;
    const int n0 = (bid % gridDim.x) * BN;

    f32x4 acc[2][NB];
    for (int mb = 0; mb < 2; mb++)
        for (int nb = 0; nb < NB; nb++)
            for (int i = 0; i < 4; i++) acc[mb][nb][i] = 0.f;

    // per-lane pre-swizzled global source pointers
    const u16* Ap = A + (m0 + w * 16 + lr) * K + swst * 8;
    const u16* Bp = B + (n0 + w * (BN / 4) + lr) * K + swst * 8;

    // prologue: tile 0 -> LDS buf 0 (async, drained by the first barrier)
    for (int j = 0; j < 2; j++)
        gl_lds16(Ap + j * 8 * K, &As[0][(w * 16 + j * 8) * 64]);
    for (int g = 0; g < NB; g++)
        gl_lds16(Bp + g * 8 * K, &Bs[0][(w * (BN / 4) + g * 8) * 64]);
    __syncthreads();

    int cur = 0;
    for (int k0 = 0; k0 < K; k0 += 64) {
        if (k0 + 64 < K) {   // prefetch next tile into the other buffer (max latency cover)
            for (int j = 0; j < 2; j++)
                gl_lds16(Ap + j * 8 * K + k0 + 64, &As[cur ^ 1][(w * 16 + j * 8) * 64]);
            for (int g = 0; g < NB; g++)
                gl_lds16(Bp + g * 8 * K + k0 + 64, &Bs[cur ^ 1][(w * (BN / 4) + g * 8) * 64]);
        }
        // compute tile k0 from buf[cur]
        bf16x8 af[2][2], bfv[NB][2];
        for (int ks = 0; ks < 2; ks++) {
            const int ch = ((ks * 4 + quad) ^ rk) * 8;
            for (int mb = 0; mb < 2; mb++)
                af[mb][ks] = *(const bf16x8*)&As[cur][(wr * 32 + mb * 16 + lcol) * 64 + ch];
            for (int nb = 0; nb < NB; nb++)
                bfv[nb][ks] = *(const bf16x8*)&Bs[cur][(wc * (BN / 2) + nb * 16 + lcol) * 64 + ch];
        }
        for (int ks = 0; ks < 2; ks++)
            for (int mb = 0; mb < 2; mb++)
                for (int nb = 0; nb < NB; nb++)
                    acc[mb][nb] = mfma16(af[mb][ks], bfv[nb][ks], acc[mb][nb]);
        __syncthreads();   // drains prefetch (vmcnt) + fences LDS reads; flip buffers
        cur ^= 1;
    }

    if (EP == 0) {
        for (int mb = 0; mb < 2; mb++)
            for (int nb = 0; nb < NB; nb++) {
                int row = m0 + wr * 32 + mb * 16 + quad * 4;
                int col = n0 + wc * (BN / 2) + nb * 16 + lcol;
                for (int i = 0; i < 4; i++)
                    Cf[(row + i) * N + col] = acc[mb][nb][i];
            }
    } else {
        const float qsc = 0.18033688011112042f;  // (1/sqrt(64)) * log2(e), folded into Q
        for (int mb = 0; mb < 2; mb++)
            for (int nb = 0; nb < NB; nb++)
                for (int i = 0; i < 4; i++) {
                    int row = m0 + wr * 32 + mb * 16 + quad * 4 + i;  // b*2048+s
                    int col = n0 + wc * (BN / 2) + nb * 16 + lcol;    // qkv column
                    int bb = row >> 11, ss = row & 2047;
                    if (col < 1024) {
                        int hh = col >> 6, dd = col & 63;
                        Qo[((bb * 16 + hh) * 2048 + ss) * 64 + dd] = f2bf(acc[mb][nb][i] * qsc);
                    } else if (col < 1280) {
                        int c = col - 1024, hh = c >> 6, dd = c & 63;
                        Ko[((bb * 4 + hh) * 2048 + ss) * 64 + dd] = f2bf(acc[mb][nb][i]);
                    } else {
                        int c = col - 1280, hh = c >> 6, dd = c & 63;
                        Vo[((bb * 4 + hh) * 64 + dd) * 2048 + ss] = f2bf(acc[mb][nb][i]);
                    }
                }
    }
}

// ---------------- flash attention, causal GQA, NO-MAX softmax, KV-SPLIT x2 ----------------
// ROUND-7 PROVEN VERSION, byte-exact revert (V-direct refuted twice: r8 vmcnt-order bug,
// r10 corrected-order still 77.7us vs 42 staged -> staged-V TLP beats per-lane V L2
// chains; family closed). 8 waves = 2 kv-split groups x 4; 80 KB LDS -> 2 blocks/CU;
// T5 setprio on MFMA clusters.
__launch_bounds__(512, 4)
__global__ void attn_kernel(const u16* __restrict__ Qg, const u16* __restrict__ Kg,
                            const u16* __restrict__ Vtg, u16* __restrict__ Og)
{
    __shared__ __align__(16) u16 Ks[2][2][64 * 64];   // [group][buf] 32 KB
    __shared__ __align__(16) u16 Vs[2][2][64 * 64];   // [group][buf] 32 KB
    __shared__ __align__(16) u16 Ps[2][64 * 64];      // [group]      16 KB  => 80 KB

    const int tid  = threadIdx.x;
    const int lane = tid & 63;
    const int w8   = tid >> 6;        // 0..7
    const int gpp  = w8 >> 2;         // kv-split group (0/1)
    const int wg   = w8 & 3;          // wave within group
    const int quad = lane >> 4;
    const int lcol = lane & 15;
    const int lr   = lane >> 3;
    const int lc   = lane & 7;
    const int swst = lc ^ lr;
    const int rk   = lcol & 7;
    const int hl   = lcol >> 3;

    const int p  = blockIdx.x;       // pair 0..15
    const int h  = blockIdx.y;
    const int b  = blockIdx.z;
    const int hk = h >> 2;

    const u16* Qp = Qg  + (b * 16 + h) * 2048 * 64;
    const u16* Kp = Kg  + (b * 4 + hk) * 2048 * 64;
    const u16* Vp = Vtg + (b * 4 + hk) * 64 * 2048;

    // P-store base: original index (w*16+quad*4+i)*64 + (((cb*2+hl)^((quad&1)*4+i))<<3)+lc
    // == (p0 + i*64) ^ (((cb*2)^i)<<3)  [all swizzle fields bit-disjoint]
    const int p0 = (wg * 16 + quad * 4) * 64 + ((hl ^ ((quad & 1) << 2)) << 3) + lc;

    float* Ob = (float*)(&Ks[1][0][0]);   // 16 KB combine buffer (valid only post-loop)
    float* Lb = (float*)(&Vs[1][0][0]);   // 64 floats

    for (int pass = 0; pass < 2; pass++) {
        const int qi = pass ? (31 - p) : p;
        const int q0 = qi * 64;
        const int nt = qi + 1;
        const int nIter = (nt + 1) >> 1;  // common (wave-uniform across block) loop count

        // Q A-fragments straight to registers; once per pass (same rows for both groups)
        bf16x8 aqr[2];
        for (int ks = 0; ks < 2; ks++)
            aqr[ks] = *(const bf16x8*)(Qp + (q0 + wg * 16 + lcol) * 64 + ks * 32 + quad * 8);

        // prologue: this group's tile 0 (ti = gpp) into buf 0 (XOR-swizzled)
        if (gpp < nt) {
            for (int j = 0; j < 2; j++) {
                const int r = wg * 16 + j * 8 + lr;
                gl_lds16(Kp + (gpp * 64 + r) * 64 + swst * 8, &Ks[gpp][0][wg * 1024 + j * 512]);
                gl_lds16(Vp + r * 2048 + gpp * 64 + swst * 8, &Vs[gpp][0][wg * 1024 + j * 512]);
            }
        }

        f32x4 o[4];
        float l_p[4];
        for (int db = 0; db < 4; db++)
            for (int i = 0; i < 4; i++) o[db][i] = 0.f;
        for (int i = 0; i < 4; i++) l_p[i] = 0.f;

        __syncthreads();

        for (int it = 0; it < nIter; ++it) {
            const int cur = it & 1;
            const int ti  = 2 * it + gpp;      // this group's tile (may be >= nt: idle)
            const int tin = ti + 2;
            if (tin < nt) {   // prefetch this group's next tile into the other buffer
                const int nbuf = cur ^ 1;
                for (int j = 0; j < 2; j++) {
                    const int r = wg * 16 + j * 8 + lr;
                    gl_lds16(Kp + (tin * 64 + r) * 64 + swst * 8, &Ks[gpp][nbuf][wg * 1024 + j * 512]);
                    gl_lds16(Vp + r * 2048 + tin * 64 + swst * 8, &Vs[gpp][nbuf][wg * 1024 + j * 512]);
                }
            }
            if (ti < nt) {
                // S = Q K^T (C layout: col=lane&15, row=quad*4+i), rows wg*16..wg*16+15
                f32x4 s[4];
                for (int cb = 0; cb < 4; cb++)
                    for (int i = 0; i < 4; i++) s[cb][i] = 0.f;
                __builtin_amdgcn_s_setprio(1);
                for (int ks = 0; ks < 2; ks++) {
                    const int chq = ((ks * 4 + quad) ^ rk) * 8;
                    for (int cb = 0; cb < 4; cb++) {
                        bf16x8 bk = *(const bf16x8*)&Ks[gpp][cur][(cb * 16 + lcol) * 64 + chq];
                        s[cb] = mfma16(aqr[ks], bk, s[cb]);
                    }
                }
                __builtin_amdgcn_s_setprio(0);

                // causal mask on the diagonal tile only (owned by group (nt-1)&1)
                if (ti == nt - 1) {
                    for (int cb = 0; cb < 4; cb++)
                        for (int i = 0; i < 4; i++) {
                            const bool masked = (cb * 16 + lcol) > (wg * 16 + quad * 4 + i);
                            s[cb][i] = masked ? -INFINITY : s[cb][i];
                        }
                }

                // no-max softmax: p = exp2(s) via raw v_exp_f32 (exp2(-inf)=0 in HW)
                for (int cb = 0; cb < 4; cb++)
                    for (int i = 0; i < 4; i++) {
                        const float pv = __builtin_amdgcn_exp2f(s[cb][i]);
                        s[cb][i] = pv;
                        l_p[i] += pv;
                    }

                // P -> LDS [r][t] swizzled (1 XOR per store), truncating f32->bf16
                for (int cb = 0; cb < 4; cb++)
                    for (int i = 0; i < 4; i++)
                        Ps[gpp][(p0 + i * 64) ^ (((cb * 2) ^ i) << 3)] =
                            (u16)(__float_as_uint(s[cb][i]) >> 16);

                // O += P V
                __builtin_amdgcn_s_setprio(1);
                for (int kt = 0; kt < 2; kt++) {
                    const int chp = ((kt * 4 + quad) ^ rk) * 8;
                    bf16x8 ap = *(const bf16x8*)&Ps[gpp][(wg * 16 + lcol) * 64 + chp];
                    for (int db = 0; db < 4; db++) {
                        bf16x8 bv = *(const bf16x8*)&Vs[gpp][cur][(db * 16 + lcol) * 64 + chp];
                        o[db] = mfma16(ap, bv, o[db]);
                    }
                }
                __builtin_amdgcn_s_setprio(0);
            }
            __syncthreads();   // single barrier per common iter: drains prefetch, flips bufs
        }

        // ---- combine the two kv-halves (partial O and l simply add; no max to merge) ----
        float lrow[4];
        for (int i = 0; i < 4; i++) {
            float l = l_p[i];
            for (int x = 1; x < 16; x <<= 1) l += __shfl_xor(l, x);
            lrow[i] = l;
        }
        if (gpp == 1) {
            for (int i = 0; i < 4; i++) {
                const int row = wg * 16 + quad * 4 + i;
                for (int db = 0; db < 4; db++)
                    Ob[row * 64 + db * 16 + lcol] = o[db][i];
                if (lcol == 0) Lb[row] = lrow[i];
            }
        }
        __syncthreads();
        if (gpp == 0) {
            for (int i = 0; i < 4; i++) {
                const int row = wg * 16 + quad * 4 + i;
                const float inv = 1.0f / (lrow[i] + Lb[row]);
                const int srow = q0 + row;
                for (int db = 0; db < 4; db++) {
                    const float val = (o[db][i] + Ob[row * 64 + db * 16 + lcol]) * inv;
                    Og[(b * 2048 + srow) * 1024 + h * 64 + db * 16 + lcol] = f2bf(val);
                }
            }
        }
        __syncthreads();   // protect Ob/Lb region before next pass restages Ks[1]/Vs[1]
    }
}

extern "C" void kernel_launch(void* const* d_in, const int* in_sizes, int n_in,
                              void* d_out, int out_size, void* d_ws, size_t ws_size,
                              hipStream_t stream) {
    const float* x     = (const float*)d_in[0];   // [2,2048,1024]
    const float* w_qkv = (const float*)d_in[1];   // [3584,1024]; only rows 0..1535 used
    const float* w_out = (const float*)d_in[2];   // [1024,1024]
    float* out = (float*)d_out;                   // [2,2048,1024] fp32
    char* ws = (char*)d_ws;

    u16* xb  = (u16*)(ws);                        // 8 MB  x as bf16 [4096,1024]
    u16* wqb = (u16*)(ws + 8  * 1024 * 1024);     // 3 MB  w_qkv[0:1536] bf16
    u16* wob = (u16*)(ws + 11 * 1024 * 1024);     // 2 MB  w_out bf16
    u16* qb  = (u16*)(ws + 13 * 1024 * 1024);     // 8 MB  Q [b,h,s,d] (pre-scaled)
    u16* kb  = (u16*)(ws + 21 * 1024 * 1024);     // 2 MB  K [b,hk,s,d]
    u16* vtb = (u16*)(ws + 23 * 1024 * 1024);     // 2 MB  V^T [b,hk,d,s]
    u16* aob = (u16*)(ws);                        // 8 MB  attn out bf16 (reuses xb)

    cvt3<<<6656, 256, 0, stream>>>(x, w_qkv, w_out, xb, wqb, wob);

    // QKV projection: 64x128 tiles -> 12 x 64 = 768 blocks (3/CU), XCD-swizzled
    gemm_rp<128, 1><<<dim3(12, 64), 256, 0, stream>>>(xb, wqb, 1536, 1024,
                                                      nullptr, qb, kb, vtb);
    // attention: 512 threads = 2 kv-split groups x 4 waves; 2 blocks/CU (80 KB LDS)
    attn_kernel<<<dim3(16, 16, 2), 512, 0, stream>>>(qb, kb, vtb, aob);
    // output projection: 64x64 tiles -> 16 x 64 = 1024 blocks (4/CU), XCD-swizzled
    gemm_rp<64, 0><<<dim3(16, 64), 256, 0, stream>>>(aob, wob, 1024, 1024,
                                                     out, nullptr, nullptr, nullptr);
}